// Round 4
// baseline (161.582 us; speedup 1.0000x reference)
//
#include <hip/hip_runtime.h>

#define T_LEN 2048
#define NSTATE 64
#define NCHUNK 16
#define CH_S 128      // stored steps per chunk = LDS buffer depth
#define WARM 64       // warm-up steps before/after the stored region
#define RK 16         // group size = renorm period = gamma batch (16 t x 4 combos)

// v_add_f32 with DPP-modified src: single fused VALU instr, no DS op.
template<int CTRL>
__device__ __forceinline__ float dpp_add(float v) {
    int r = __builtin_amdgcn_update_dpp(0, __float_as_int(v), CTRL, 0xF, 0xF, true);
    return v + __int_as_float(r);
}

// Pure-DPP 64-lane sum to lane 63 (row_shr 1,2,4,8 + row_bcast15/31).
__device__ __forceinline__ float dpp_sum_to63(float v) {
    v = dpp_add<0x111>(v);
    v = dpp_add<0x112>(v);
    v = dpp_add<0x114>(v);
    v = dpp_add<0x118>(v);
    v = dpp_add<0x142>(v);
    v = dpp_add<0x143>(v);
    return v;
}

// Full-wave sum broadcast via v_readlane — zero DS ops.
__device__ __forceinline__ float wave_total(float v) {
    float s = dpp_sum_to63(v);
    return __int_as_float(__builtin_amdgcn_readlane(__float_as_int(s), 63));
}

// v + v[lane^1] via DPP quad_perm [1,0,3,2].
__device__ __forceinline__ float pair_sum_xor1(float v) {
    int r = __builtin_amdgcn_update_dpp(0, __float_as_int(v), 0xB1, 0xF, 0xF, true);
    return v + __int_as_float(r);
}

// raw bpermute: addrb is BYTE address (lane_idx*4)
__device__ __forceinline__ float bperm(int addrb, float v) {
    return __int_as_float(__builtin_amdgcn_ds_bpermute(addrb, __float_as_int(v)));
}

// cheap fp32 -> bf16 (round-half-up)
__device__ __forceinline__ unsigned short bf16_of(float f) {
    return (unsigned short)((__float_as_uint(f) + 0x8000u) >> 16);
}

// GEN_POLY = ('1111001','1011011'), mu=6, NS=64.
// o0 parity mask 57, o1 mask 27.  x(s,t) = kE*(la_t + c0(s)*l0_t + c1(s)*l1_t),
// gamma(s,0)=2^x, gamma(s,1)=2^-x, to(s,b) = (b<<5)|(s>>1), kE = 0.5*log2(e).
//
// Gamma batch: x has only 4 distinct values per t (signs of l0,l1). For a
// 16-step group, lane (t<<2)|q computes 2^{kE*(la_t +/- l0_t +/- l1_t)}:
// ONE v_exp_f32 + ONE v_rcp_f32 per 16 steps. Consumers gather via bpermute
// from lane (t<<2)|q(s), q(s) = parity(s&57) | parity(s&27)<<1.

struct Ctx {
    const float* chp;
    const float* lap;
    int tl;        // lane>>2 : which t of the group this lane evaluates
    int qb;        // q(s)*4  : byte base for gamma gathers
    unsigned m0;   // sign mask for l0 in batch (from lane&1)
    unsigned m1;   // sign mask for l1 in batch (from lane&2)
};

__device__ __forceinline__ void load_grp(const Ctx& c, int gg, float& la, float2& ch) {
    la = c.lap[gg + c.tl];
    ch = ((const float2*)c.chp)[gg + c.tl];
}

__device__ __forceinline__ void make_ER(const Ctx& c, float la, float2 ch,
                                        float& E, float& R) {
    const float kE = 0.5f * 1.442695040888963f;
    float x0 = __uint_as_float(__float_as_uint(ch.x) ^ c.m0);
    float x1 = __uint_as_float(__float_as_uint(ch.y) ^ c.m1);
    float xv = kE * (la + x0 + x1);
    E = exp2f(xv);                      // gamma0 batch
    R = __builtin_amdgcn_rcpf(E);       // gamma1 batch
}

// ---- fwd 16-step group; stores alpha_t (bf16) into LDS when STORE ----
template<bool STORE>
__device__ __forceinline__ float fwd_group(const Ctx& c, float state, float E, float R,
                                           unsigned short* alds, int g, int t0,
                                           int lane, int fselb) {
    #pragma unroll
    for (int i = 0; i < RK; ++i) {
        if (STORE) alds[(g + i - t0) * NSTATE + lane] = bf16_of(state);
        int ab = c.qb + (i << 4);              // byte addr of lane (i<<2)|q
        float g0v = bperm(ab, E);
        float g1v = bperm(ab, R);
        float s0 = pair_sum_xor1(state * g0v); // pair sums (alpha*gamma0)
        float s1 = pair_sum_xor1(state * g1v);
        float v  = (lane & 1) ? s1 : s0;       // even lane carries s0, odd s1
        state = bperm(fselb, v);               // dest j <- lane 2(j&31)+(j>>5)
    }
    float s = wave_total(state);
    return state * __builtin_amdgcn_rcpf(s);
}

// ---- bwd 16-step group; fused LLR from LDS alpha when LLR ----
template<bool LLR>
__device__ __forceinline__ float bwd_group(const Ctx& c, float state, float E, float R,
                                           const unsigned short* alds, float* outp,
                                           int g, int t0, int lane,
                                           int bs0b, int bs1b) {
    float av[RK];
    if (LLR) {
        #pragma unroll
        for (int i = 0; i < RK; ++i)
            av[i] = __uint_as_float(((unsigned)alds[(g + i - t0) * NSTATE + lane]) << 16);
    }
    #pragma unroll
    for (int i = RK - 1; i >= 0; --i) {
        int ab = c.qb + (i << 4);
        float g0v = bperm(ab, E);
        float g1v = bperm(ab, R);
        float t0v = bperm(bs0b, state);        // beta_{t+1}[s>>1]
        float t1v = bperm(bs1b, state);        // beta_{t+1}[32+(s>>1)]
        float p0 = g0v * t0v;
        float p1 = g1v * t1v;
        if (LLR) {
            float na = av[i] * p0;             // n0 partial of state s
            float nb = av[i] * p1;             // n1 partial
            na += __shfl_xor(na, 32, 64);
            nb += __shfl_xor(nb, 32, 64);
            float z = (lane >= 32) ? nb : na;  // lo half: n0, hi half: n1
            z = dpp_add<0xB1>(z);              // xor1
            z = dpp_add<0x4E>(z);              // xor2
            z = dpp_add<0x124>(z);             // row_ror:4
            z = dpp_add<0x128>(z);             // row_ror:8 -> row-of-16 sums
            z += __shfl_xor(z, 16, 64);        // halves complete
            float lg = __log2f(z);             // one log covers n0 AND n1
            float d  = (lg - __shfl_xor(lg, 32, 64)) * 0.6931471805599453f;
            if (lane == 0) outp[g + i] = d;
        }
        state = p0 + p1;                       // beta_t
    }
    float s = wave_total(state);
    return state * __builtin_amdgcn_rcpf(s);
}

// ---------------- Fused kernel: wave 0 = fwd (alpha->LDS), wave 1 = bwd+LLR ----------------
__global__ __launch_bounds__(128, 4)
void bcjr_fused_kernel(const float* __restrict__ llr_ch,   // [B][2*T]
                       const float* __restrict__ llr_a,    // [B][T]
                       float* __restrict__ out)            // [B][T]
{
    __shared__ unsigned short alds[CH_S * NSTATE];   // 16 KiB

    const int lane  = threadIdx.x & 63;
    const int role  = threadIdx.x >> 6;
    const int unit  = blockIdx.x;
    const int chunk = unit & (NCHUNK - 1);
    const int b     = unit >> 4;

    Ctx c;
    c.chp = llr_ch + (size_t)b * (2 * T_LEN);
    c.lap = llr_a  + (size_t)b * T_LEN;
    c.tl  = lane >> 2;
    c.m0  = (unsigned)(lane & 1) << 31;
    c.m1  = (unsigned)((lane >> 1) & 1) << 31;
    const int q = (__popc(lane & 57) & 1) | ((__popc(lane & 27) & 1) << 1);
    c.qb  = q << 2;
    const int t0 = chunk * CH_S;

    if (role == 0) {
        // ---- forward wave ----
        const int fselb = (2 * (lane & 31) + (lane >> 5)) << 2;
        float state = (chunk == 0) ? ((lane == 0) ? 1.0f : 0.0f) : (1.0f / 64.0f);
        const int ts   = (chunk == 0) ? t0 : t0 - WARM;
        const int tend = t0 + CH_S;
        float laC; float2 chC;
        load_grp(c, ts, laC, chC);
        for (int g = ts; g < tend; g += RK) {
            int gn = (g + RK < tend) ? g + RK : g;     // prefetch next group
            float laN; float2 chN;
            load_grp(c, gn, laN, chN);
            float E, R; make_ER(c, laC, chC, E, R);
            if (g < t0) state = fwd_group<false>(c, state, E, R, alds, g, t0, lane, fselb);
            else        state = fwd_group<true >(c, state, E, R, alds, g, t0, lane, fselb);
            laC = laN; chC = chN;
        }
        __syncthreads();   // publish alpha
    } else {
        // ---- backward wave ----
        const int bs0b = (lane >> 1) << 2;
        const int bs1b = bs0b + 128;
        float state = 1.0f / 64.0f;          // exact beta_T for the last chunk
        const int te = (chunk == NCHUNK - 1) ? (t0 + CH_S) : (t0 + CH_S + WARM);
        float* outp = out + (size_t)b * T_LEN;
        float laC; float2 chC;
        load_grp(c, te - RK, laC, chC);
        for (int g = te - RK; g >= t0 + CH_S; g -= RK) {   // warm-up
            int gn = (g - RK >= t0) ? g - RK : g;
            float laN; float2 chN;
            load_grp(c, gn, laN, chN);
            float E, R; make_ER(c, laC, chC, E, R);
            state = bwd_group<false>(c, state, E, R, alds, nullptr, g, t0, lane, bs0b, bs1b);
            laC = laN; chC = chN;
        }
        __syncthreads();   // wait for alpha
        for (int g = t0 + CH_S - RK; g >= t0; g -= RK) {   // stored region + LLR
            int gn = (g - RK >= t0) ? g - RK : g;
            float laN; float2 chN;
            load_grp(c, gn, laN, chN);
            float E, R; make_ER(c, laC, chC, E, R);
            state = bwd_group<true>(c, state, E, R, alds, outp, g, t0, lane, bs0b, bs1b);
            laC = laN; chC = chN;
        }
    }
}

extern "C" void kernel_launch(void* const* d_in, const int* in_sizes, int n_in,
                              void* d_out, int out_size, void* d_ws, size_t ws_size,
                              hipStream_t stream) {
    const float* llr_ch = (const float*)d_in[0];
    const float* llr_a  = (const float*)d_in[1];
    float* out = (float*)d_out;

    int B = in_sizes[0] / (2 * T_LEN);   // 256
    (void)d_ws; (void)ws_size;

    int n_units = B * NCHUNK;            // 4096 blocks (1 chunk each, 2 waves)
    hipLaunchKernelGGL(bcjr_fused_kernel, dim3(n_units), dim3(128), 0, stream,
                       llr_ch, llr_a, out);
}